// Round 8
// baseline (170.795 us; speedup 1.0000x reference)
//
#include <hip/hip_runtime.h>
#include <hip/hip_bf16.h>
#include <stdint.h>

#define SEQ 4096
#define DH  64
#define KT  32                 // keys per iteration per key-half
#define PS  40                 // sP row stride in ushorts (80 B)
#define NIT ((SEQ / 2) / KT)   // 64 iterations
#define QSCALE 0.090168440f    // log2(e)/16 folded into Q

typedef __attribute__((ext_vector_type(8))) short short8;
typedef __attribute__((ext_vector_type(4))) float floatx4;

__device__ __forceinline__ ushort f2bf_rne(float f) {
    unsigned u = __float_as_uint(f);
    unsigned r = u + 0x7FFFu + ((u >> 16) & 1u);
    return (ushort)(r >> 16);
}

// ---- prep: K,V -> bf16 in MFMA-fragment-permuted order (unchanged from v7) ----
__global__ __launch_bounds__(256)
void prep_kv(const float* __restrict__ K, const float* __restrict__ V,
             ushort* __restrict__ Kf, ushort* __restrict__ Vf) {
    const int bh = blockIdx.y, kb0 = blockIdx.x * 128, t = threadIdx.x;
    const size_t inB = ((size_t)bh * SEQ + kb0) * DH;
    {   // K part: 4 passes x 256 threads = 1024 chunks (8 groups of 16 keys)
        const float* srcB = K + inB;
        ushort* dstB = Kf + (size_t)bh * SEQ * DH + (size_t)(kb0 >> 4) * 1024;
        #pragma unroll
        for (int p = 0; p < 4; ++p) {
            int c   = p * 256 + t;
            int g   = c >> 7, rem = c & 127;
            int tt  = rem >> 6, lam = rem & 63;
            int key = g * 16 + (lam & 15);
            int d0  = tt * 32 + (lam >> 4) * 8;
            const float* s = srcB + (size_t)key * DH + d0;
            float4 a = *(const float4*)s;
            float4 b = *(const float4*)(s + 4);
            short8 o;
            o[0] = (short)f2bf_rne(a.x); o[1] = (short)f2bf_rne(a.y);
            o[2] = (short)f2bf_rne(a.z); o[3] = (short)f2bf_rne(a.w);
            o[4] = (short)f2bf_rne(b.x); o[5] = (short)f2bf_rne(b.y);
            o[6] = (short)f2bf_rne(b.z); o[7] = (short)f2bf_rne(b.w);
            *(short8*)(dstB + g * 1024 + tt * 512 + lam * 8) = o;
        }
    }
    {   // V part: 4d x 8key register transpose into permuted chunks
        const int d0 = (t & 15) * 4, sl = (t >> 4) * 8;
        const float* src = V + inB + (size_t)sl * DH + d0;
        ushort* dstB = Vf + (size_t)bh * SEQ * DH + (size_t)(kb0 >> 5) * 2048;
        ushort b[8][4];
        #pragma unroll
        for (int r = 0; r < 8; ++r) {
            float4 f = *(const float4*)(src + r * DH);
            b[r][0] = f2bf_rne(f.x); b[r][1] = f2bf_rne(f.y);
            b[r][2] = f2bf_rne(f.z); b[r][3] = f2bf_rne(f.w);
        }
        const int Tl = sl >> 5, kq = (sl & 31) >> 3;
        #pragma unroll
        for (int i = 0; i < 4; ++i) {
            int d = d0 + i;
            short8 w;
            #pragma unroll
            for (int r = 0; r < 8; ++r) w[r] = (short)b[r][i];
            *(short8*)(dstB + Tl * 2048 + (d >> 4) * 512 + kq * 128 + (d & 15) * 8) = w;
        }
    }
}

// ---- main: barrier-free, software-pipelined P round-trip (double-buffered sP) ----
__global__ __launch_bounds__(256, 4)
void attn_fwd_v8(const float* __restrict__ Q, const ushort* __restrict__ Kf,
                 const ushort* __restrict__ Vf, float* __restrict__ O)
{
    __shared__ __align__(16) char smem[20480];   // 4 waves x 2 bufs x 2560 B; epilogue overlays

    // XCD-locality swizzle: 2 bh per XCD
    const int g    = blockIdx.x;
    const int bh   = (g & 7) * 2 + ((g >> 3) & 1);
    const int qt0  = (g >> 4) * 64;

    const int tid   = threadIdx.x;
    const int wave  = tid >> 6;
    const int widx  = wave & 1;    // q-half
    const int wpair = wave >> 1;   // key-half
    const int lane  = tid & 63;
    const int n16   = lane & 15;
    const int quad  = lane >> 4;

    const float* Qb  = Q + ((size_t)bh * SEQ) * DH;
    const char*  KfB = (const char*)(Kf + (size_t)bh * SEQ * DH);
    const char*  VfB = (const char*)(Vf + (size_t)bh * SEQ * DH);
    float*       Ob  = O + ((size_t)bh * SEQ) * DH;

    ushort* sPw = (ushort*)smem + wave * 2560;   // two 1280-ushort buffers per wave

    // Q B-frags; log2(e)/16 folded (exp2 arg = raw score)
    const int qw0 = qt0 + widx * 32;
    short8 qfrag[2][2];
    #pragma unroll
    for (int qt = 0; qt < 2; ++qt) {
        const float* qrow = Qb + (size_t)(qw0 + qt * 16 + n16) * DH;
        #pragma unroll
        for (int t = 0; t < 2; ++t) {
            const float* p = qrow + t * 32 + quad * 8;
            short8 a;
            #pragma unroll
            for (int j = 0; j < 8; ++j) a[j] = (short)f2bf_rne(p[j] * QSCALE);
            qfrag[qt][t] = a;
        }
    }
    short8 ones;
    #pragma unroll
    for (int j = 0; j < 8; ++j) ones[j] = (short)0x3F80;   // bf16 1.0

    floatx4 oacc[2][4];
    floatx4 lacc[2];
    #pragma unroll
    for (int qt = 0; qt < 2; ++qt) {
        lacc[qt] = (floatx4){0.f, 0.f, 0.f, 0.f};
        #pragma unroll
        for (int nt = 0; nt < 4; ++nt) oacc[qt][nt] = (floatx4){0.f, 0.f, 0.f, 0.f};
    }

    // per-lane base pointers (lane*16 folded); tiles are 4096-B fragment blocks
    const char* kp0 = KfB + (size_t)wpair * 262144 + lane * 16;
    const char* vp0 = VfB + (size_t)wpair * 262144 + lane * 16;

    short8 kf[4], vf[4];
    #pragma unroll
    for (int c = 0; c < 4; ++c) kf[c] = *(const short8*)(kp0 + c * 1024);
    #pragma unroll
    for (int c = 0; c < 4; ++c) vf[c] = *(const short8*)(vp0 + c * 1024);

    // ---- prologue: QK(0), exp(0) -> sP buf0; kf advances to tile 1 ----
    {
        floatx4 sacc[2][2];
        #pragma unroll
        for (int kt = 0; kt < 2; ++kt)
            #pragma unroll
            for (int qt = 0; qt < 2; ++qt) {
                floatx4 acc = (floatx4){0.f, 0.f, 0.f, 0.f};
                acc = __builtin_amdgcn_mfma_f32_16x16x32_bf16(kf[kt * 2 + 0], qfrag[qt][0], acc, 0, 0, 0);
                acc = __builtin_amdgcn_mfma_f32_16x16x32_bf16(kf[kt * 2 + 1], qfrag[qt][1], acc, 0, 0, 0);
                sacc[kt][qt] = acc;
            }
        #pragma unroll
        for (int c = 0; c < 4; ++c) kf[c] = *(const short8*)(kp0 + 4096 + c * 1024);
        #pragma unroll
        for (int kt = 0; kt < 2; ++kt)
            #pragma unroll
            for (int qt = 0; qt < 2; ++qt) {
                unsigned u0 = __float_as_uint(__builtin_amdgcn_exp2f(sacc[kt][qt][0]));
                unsigned u1 = __float_as_uint(__builtin_amdgcn_exp2f(sacc[kt][qt][1]));
                unsigned u2 = __float_as_uint(__builtin_amdgcn_exp2f(sacc[kt][qt][2]));
                unsigned u3 = __float_as_uint(__builtin_amdgcn_exp2f(sacc[kt][qt][3]));
                uint2 w;
                w.x = __builtin_amdgcn_perm(u1, u0, 0x07060302);
                w.y = __builtin_amdgcn_perm(u3, u2, 0x07060302);
                *(uint2*)&sPw[(qt * 16 + n16) * PS + kt * 16 + quad * 4] = w;
            }
    }

    const char* kp = kp0 + 4096;   // tile currently in kf
    const char* vp = vp0;          // tile currently in vf

    // ---- pipelined main loop: PV lags QK/exp by one tile ----
    for (int it = 0; it < NIT - 1; ++it) {
        // read P(it) — written last iteration (or prologue); ~full-iter distance
        const ushort* pb = sPw + (it & 1) * 1280;
        short8 pf0 = *(const short8*)&pb[(0 * 16 + n16) * PS + quad * 8];
        short8 pf1 = *(const short8*)&pb[(1 * 16 + n16) * PS + quad * 8];

        // QK(it+1) on kf (tile it+1)
        floatx4 sacc[2][2];
        #pragma unroll
        for (int kt = 0; kt < 2; ++kt)
            #pragma unroll
            for (int qt = 0; qt < 2; ++qt) {
                floatx4 acc = (floatx4){0.f, 0.f, 0.f, 0.f};
                acc = __builtin_amdgcn_mfma_f32_16x16x32_bf16(kf[kt * 2 + 0], qfrag[qt][0], acc, 0, 0, 0);
                acc = __builtin_amdgcn_mfma_f32_16x16x32_bf16(kf[kt * 2 + 1], qfrag[qt][1], acc, 0, 0, 0);
                sacc[kt][qt] = acc;
            }

        // prefetch kf <- tile it+2 (clamped; dead re-read on last iter)
        const char* kpn = (it + 2 < NIT) ? kp + 4096 : kp;
        #pragma unroll
        for (int c = 0; c < 4; ++c) kf[c] = *(const short8*)(kpn + c * 1024);
        kp = kpn;

        // exp(it+1) -> write P into the other buffer
        ushort* wb = sPw + ((it + 1) & 1) * 1280;
        #pragma unroll
        for (int kt = 0; kt < 2; ++kt)
            #pragma unroll
            for (int qt = 0; qt < 2; ++qt) {
                unsigned u0 = __float_as_uint(__builtin_amdgcn_exp2f(sacc[kt][qt][0]));
                unsigned u1 = __float_as_uint(__builtin_amdgcn_exp2f(sacc[kt][qt][1]));
                unsigned u2 = __float_as_uint(__builtin_amdgcn_exp2f(sacc[kt][qt][2]));
                unsigned u3 = __float_as_uint(__builtin_amdgcn_exp2f(sacc[kt][qt][3]));
                uint2 w;
                w.x = __builtin_amdgcn_perm(u1, u0, 0x07060302);
                w.y = __builtin_amdgcn_perm(u3, u2, 0x07060302);
                *(uint2*)&wb[(qt * 16 + n16) * PS + kt * 16 + quad * 4] = w;
            }

        // PV(it) on vf (tile it) with pf; l += ones·P^T
        #pragma unroll
        for (int nt = 0; nt < 4; ++nt) {
            short8 v = vf[nt];
            oacc[0][nt] = __builtin_amdgcn_mfma_f32_16x16x32_bf16(v, pf0, oacc[0][nt], 0, 0, 0);
            oacc[1][nt] = __builtin_amdgcn_mfma_f32_16x16x32_bf16(v, pf1, oacc[1][nt], 0, 0, 0);
        }
        lacc[0] = __builtin_amdgcn_mfma_f32_16x16x32_bf16(ones, pf0, lacc[0], 0, 0, 0);
        lacc[1] = __builtin_amdgcn_mfma_f32_16x16x32_bf16(ones, pf1, lacc[1], 0, 0, 0);

        // prefetch vf <- tile it+1 (consumed next iteration's PV)
        vp += 4096;
        #pragma unroll
        for (int c = 0; c < 4; ++c) vf[c] = *(const short8*)(vp + c * 1024);
    }

    // ---- tail: PV(NIT-1) ----
    {
        const ushort* pb = sPw + ((NIT - 1) & 1) * 1280;
        short8 pf0 = *(const short8*)&pb[(0 * 16 + n16) * PS + quad * 8];
        short8 pf1 = *(const short8*)&pb[(1 * 16 + n16) * PS + quad * 8];
        #pragma unroll
        for (int nt = 0; nt < 4; ++nt) {
            short8 v = vf[nt];
            oacc[0][nt] = __builtin_amdgcn_mfma_f32_16x16x32_bf16(v, pf0, oacc[0][nt], 0, 0, 0);
            oacc[1][nt] = __builtin_amdgcn_mfma_f32_16x16x32_bf16(v, pf1, oacc[1][nt], 0, 0, 0);
        }
        lacc[0] = __builtin_amdgcn_mfma_f32_16x16x32_bf16(ones, pf0, lacc[0], 0, 0, 0);
        lacc[1] = __builtin_amdgcn_mfma_f32_16x16x32_bf16(ones, pf1, lacc[1], 0, 0, 0);
    }

    // ---- epilogue: combine key-halves through LDS (overlay), store O ----
    __syncthreads();
    float* epiO = (float*)smem;               // [widx*32+q][68] fp32
    float* epiL = (float*)(smem + 17408);     // [64]
    if (wpair == 1) {
        #pragma unroll
        for (int qt = 0; qt < 2; ++qt) {
            const int row = widx * 32 + qt * 16 + n16;
            #pragma unroll
            for (int nt = 0; nt < 4; ++nt)
                *(float4*)&epiO[row * 68 + nt * 16 + quad * 4] = (float4){
                    oacc[qt][nt][0], oacc[qt][nt][1], oacc[qt][nt][2], oacc[qt][nt][3]};
            if (quad == 0) epiL[row] = lacc[qt][0];
        }
    }
    __syncthreads();
    if (wpair == 0) {
        #pragma unroll
        for (int qt = 0; qt < 2; ++qt) {
            const int row = widx * 32 + qt * 16 + n16;
            const float inv = 1.0f / (lacc[qt][0] + epiL[row]);
            const int q = qw0 + qt * 16 + n16;
            #pragma unroll
            for (int nt = 0; nt < 4; ++nt) {
                float4 part = *(const float4*)&epiO[row * 68 + nt * 16 + quad * 4];
                float4 o;
                o.x = (oacc[qt][nt][0] + part.x) * inv;
                o.y = (oacc[qt][nt][1] + part.y) * inv;
                o.z = (oacc[qt][nt][2] + part.z) * inv;
                o.w = (oacc[qt][nt][3] + part.w) * inv;
                *(float4*)&Ob[(size_t)q * DH + nt * 16 + quad * 4] = o;
            }
        }
    }
}

// ---------------- fallback (fp32-direct) if ws too small ----------------
__global__ __launch_bounds__(256, 4)
void attn_fwd_v1(const float* __restrict__ Q, const float* __restrict__ K,
                 const float* __restrict__ V, float* __restrict__ O)
{
    __shared__ __align__(16) ushort sKf[64 * 72];
    __shared__ __align__(16) ushort sVf[64 * 72];
    __shared__ __align__(16) ushort sPf[4 * 16 * 72];
    const int bh = blockIdx.y, qt0 = blockIdx.x * 64, tid = threadIdx.x;
    const int wave = tid >> 6, lane = tid & 63, n16 = lane & 15, quad = lane >> 4;
    const size_t base = (size_t)bh * SEQ * DH;
    const float *Qb = Q + base, *Kb = K + base, *Vb = V + base;
    float* Ob = O + base;
    short8 qfrag[2];
    {
        const float* qrow = Qb + (size_t)(qt0 + wave * 16 + n16) * DH;
        #pragma unroll
        for (int t = 0; t < 2; ++t) {
            const float* p = qrow + t * 32 + quad * 8;
            short8 a;
            #pragma unroll
            for (int j = 0; j < 8; ++j) a[j] = (short)f2bf_rne(p[j] * 0.0625f);
            qfrag[t] = a;
        }
    }
    floatx4 oacc[4];
    #pragma unroll
    for (int nt = 0; nt < 4; ++nt) oacc[nt] = (floatx4){0.f,0.f,0.f,0.f};
    float m_i[4] = {-INFINITY,-INFINITY,-INFINITY,-INFINITY};
    float l_i[4] = {0.f,0.f,0.f,0.f};
    const int skr = tid >> 2, sc0 = (tid & 3) * 16;
    for (int kt0 = 0; kt0 < SEQ; kt0 += 64) {
        __syncthreads();
        const float* ksrc = Kb + (size_t)(kt0 + skr) * DH + sc0;
        const float* vsrc = Vb + (size_t)(kt0 + skr) * DH + sc0;
        ushort* kdst = &sKf[skr * 72 + sc0];
        #pragma unroll
        for (int i = 0; i < 16; i += 4) {
            float4 kf = *(const float4*)(ksrc + i);
            kdst[i+0]=f2bf_rne(kf.x); kdst[i+1]=f2bf_rne(kf.y);
            kdst[i+2]=f2bf_rne(kf.z); kdst[i+3]=f2bf_rne(kf.w);
            float4 vf = *(const float4*)(vsrc + i);
            sVf[(sc0+i+0)*72+skr]=f2bf_rne(vf.x); sVf[(sc0+i+1)*72+skr]=f2bf_rne(vf.y);
            sVf[(sc0+i+2)*72+skr]=f2bf_rne(vf.z); sVf[(sc0+i+3)*72+skr]=f2bf_rne(vf.w);
        }
        __syncthreads();
        floatx4 sacc[4];
        #pragma unroll
        for (int nt = 0; nt < 4; ++nt) {
            sacc[nt] = (floatx4){0.f,0.f,0.f,0.f};
            #pragma unroll
            for (int t = 0; t < 2; ++t) {
                short8 b = *(const short8*)&sKf[(nt*16+n16)*72 + t*32 + quad*8];
                sacc[nt] = __builtin_amdgcn_mfma_f32_16x16x32_bf16(qfrag[t], b, sacc[nt], 0,0,0);
            }
        }
        ushort* pw = &sPf[wave * 16 * 72];
        #pragma unroll
        for (int r = 0; r < 4; ++r) {
            float mx = fmaxf(fmaxf(sacc[0][r],sacc[1][r]),fmaxf(sacc[2][r],sacc[3][r]));
            #pragma unroll
            for (int off = 1; off < 16; off <<= 1) mx = fmaxf(mx, __shfl_xor(mx, off, 64));
            float mnew = fmaxf(m_i[r], mx);
            float alpha = __expf(m_i[r] - mnew);
            m_i[r] = mnew;
            float sum = 0.f;
            #pragma unroll
            for (int nt = 0; nt < 4; ++nt) {
                float p = __expf(sacc[nt][r] - mnew);
                sacc[nt][r] = p; sum += p;
            }
            #pragma unroll
            for (int off = 1; off < 16; off <<= 1) sum += __shfl_xor(sum, off, 64);
            l_i[r] = l_i[r] * alpha + sum;
            #pragma unroll
            for (int nt = 0; nt < 4; ++nt) oacc[nt][r] *= alpha;
            #pragma unroll
            for (int nt = 0; nt < 4; ++nt)
                pw[(quad*4+r)*72 + nt*16 + n16] = f2bf_rne(sacc[nt][r]);
        }
        #pragma unroll
        for (int t = 0; t < 2; ++t) {
            short8 pfr = *(const short8*)&pw[n16*72 + t*32 + quad*8];
            #pragma unroll
            for (int nt = 0; nt < 4; ++nt) {
                short8 vfr = *(const short8*)&sVf[(nt*16+n16)*72 + t*32 + quad*8];
                oacc[nt] = __builtin_amdgcn_mfma_f32_16x16x32_bf16(pfr, vfr, oacc[nt], 0,0,0);
            }
        }
    }
    #pragma unroll
    for (int r = 0; r < 4; ++r) {
        float inv = 1.0f / l_i[r];
        float* orow = Ob + (size_t)(qt0 + wave*16 + quad*4 + r) * DH;
        #pragma unroll
        for (int nt = 0; nt < 4; ++nt) orow[nt*16+n16] = oacc[nt][r] * inv;
    }
}

extern "C" void kernel_launch(void* const* d_in, const int* in_sizes, int n_in,
                              void* d_out, int out_size, void* d_ws, size_t ws_size,
                              hipStream_t stream) {
    const float* q = (const float*)d_in[0];
    const float* k = (const float*)d_in[1];
    const float* v = (const float*)d_in[2];
    float* o = (float*)d_out;
    const size_t elems = (size_t)16 * SEQ * DH;
    const size_t need  = elems * 2 * 2;     // Kf + Vf, bf16
    if (ws_size >= need) {
        ushort* kf = (ushort*)d_ws;
        ushort* vf = kf + elems;
        prep_kv<<<dim3(SEQ / 128, 16), dim3(256), 0, stream>>>(k, v, kf, vf);
        attn_fwd_v8<<<dim3(1024), dim3(256), 0, stream>>>(q, kf, vf, o);
    } else {
        attn_fwd_v1<<<dim3(SEQ / 64, 16), dim3(256), 0, stream>>>(q, k, v, o);
    }
}